// Round 6
// baseline (135.269 us; speedup 1.0000x reference)
//
#include <hip/hip_runtime.h>

#define TT 256      // T
#define DD 256      // D = H*DK
#define NH 4
#define DKK 64
#define NR 64
#define NB 4        // batch

#define FMA4(A, S, V) { A.x += (S)*(V).x; A.y += (S)*(V).y; A.z += (S)*(V).z; A.w += (S)*(V).w; }

// ---------------- Kernel 1: fused QKV projection ----------------
// grid (64 row-tiles of 16, 4 col-tiles of 64, 3 projections), block 256.
// (measured healthy in round 5; untouched)
__global__ __launch_bounds__(256) void k_qkv(
    const float* __restrict__ x,
    const float* __restrict__ Wq, const float* __restrict__ bq,
    const float* __restrict__ Wk, const float* __restrict__ bk,
    const float* __restrict__ Wv, const float* __restrict__ bv,
    float* __restrict__ Q, float* __restrict__ K, float* __restrict__ V)
{
    const int z = blockIdx.z;
    const float* __restrict__ W    = (z == 0) ? Wq : (z == 1) ? Wk : Wv;
    const float* __restrict__ bias = (z == 0) ? bq : (z == 1) ? bk : bv;
    float* __restrict__ out        = (z == 0) ? Q  : (z == 1) ? K  : V;
    const int r0 = blockIdx.x * 16, c0 = blockIdx.y * 64;
    __shared__ float xl[16][68];
    __shared__ float wl[64][68];
    const int t = threadIdx.x;
    const int cg = t & 15, rg = t >> 4;
    float acc[4] = {};
    for (int kt = 0; kt < 4; ++kt) {
        const int kb = kt * 64;
        {
            const int r = t >> 4, q4 = t & 15;
            *(float4*)&xl[r][q4 * 4] = *(const float4*)&x[(r0 + r) * DD + kb + q4 * 4];
        }
        #pragma unroll
        for (int u = 0; u < 4; ++u) {
            const int idx = u * 256 + t;
            const int r = idx >> 4, q4 = idx & 15;
            *(float4*)&wl[r][q4 * 4] = *(const float4*)&W[(c0 + r) * DD + kb + q4 * 4];
        }
        __syncthreads();
        #pragma unroll 4
        for (int d4 = 0; d4 < 64; d4 += 4) {
            const float4 xv = *(const float4*)&xl[rg][d4];
            #pragma unroll
            for (int c = 0; c < 4; ++c) {
                const float4 wv = *(const float4*)&wl[cg + 16 * c][d4];
                acc[c] += xv.x * wv.x + xv.y * wv.y + xv.z * wv.z + xv.w * wv.w;
            }
        }
        __syncthreads();
    }
    const int r = r0 + rg;
    #pragma unroll
    for (int c = 0; c < 4; ++c) {
        const int cc = c0 + cg + 16 * c;
        out[r * DD + cc] = acc[c] + bias[cc];
    }
}

// ---------------- Kernel 2: relational attention (rebuilt, normal-shaped) ----
// grid (16 i-tiles of 16, H, B) = 256 blocks, block 256, LDS 49.5 KB.
// K, V, rel_k, rel_v read from GLOBAL (L2-resident; 16x reuse across i-tiles).
// Restructurings (HW-verified correct in round 5):
//   q.(k_j + rel_k[sm_ij]) = q.k_j + qr[i, sm_ij]
//   sum_j p_ij (v_j + rel_v[sm_ij]) = P.V + sum_r w[i,r] rel_v_r
__global__ __launch_bounds__(256) void k_attn(
    const float* __restrict__ Q, const float* __restrict__ K, const float* __restrict__ V,
    const int* __restrict__ SM,
    const float* __restrict__ relk, const float* __restrict__ relv,
    float* __restrict__ AGG)
{
    const int it = blockIdx.x, h = blockIdx.y, b = blockIdx.z;
    const int i0 = it * 16;
    __shared__ float ql[16][68];             //  4.3 KB
    __shared__ unsigned char smlp[16][256];  //  4.0 KB (ids < 64 fit u8)
    __shared__ float sl[16][260];            // 16.6 KB scores -> probs
    __shared__ float qrl[16][64];            //  4.0 KB q . rel_k
    __shared__ float wlh[16][64];            //  4.0 KB histogram
    __shared__ float aggp[4][16][68];        // 17.4 KB PV partials (per wave)

    const int t = threadIdx.x;

    // ---- stage Q + packed SM, zero histogram ----
    {
        const int r = t >> 4, q4 = t & 15;
        *(float4*)&ql[r][q4 * 4] = *(const float4*)&Q[(b * TT + i0 + r) * DD + h * DKK + q4 * 4];
    }
    #pragma unroll
    for (int u = 0; u < 4; ++u) {
        const int idx = u * 256 + t;             // 1024 int4 total
        const int i = idx >> 6, j4 = idx & 63;
        const int4 s4 = *(const int4*)&SM[(b * TT + i0 + i) * TT + j4 * 4];
        const unsigned int pk = (unsigned int)(s4.x & 255) | ((unsigned int)(s4.y & 255) << 8)
                              | ((unsigned int)(s4.z & 255) << 16) | ((unsigned int)(s4.w & 255) << 24);
        *(unsigned int*)&smlp[i][j4 * 4] = pk;
    }
    {
        float* wf = &wlh[0][0];
        wf[t] = 0.f; wf[t + 256] = 0.f; wf[t + 512] = 0.f; wf[t + 768] = 0.f;
    }
    __syncthreads();

    // ---- qr[i][r] = q_i . rel_k_r : r = t&63, 4 i's per wave (ig = t>>6) ----
    {
        const int r = t & 63, ig = t >> 6;
        const float* __restrict__ rk = &relk[r * DD + h * DKK];
        float a0 = 0.f, a1 = 0.f, a2 = 0.f, a3 = 0.f;
        #pragma unroll 4
        for (int d4 = 0; d4 < 64; d4 += 4) {
            const float4 rk4 = *(const float4*)&rk[d4];
            const float4 q0 = *(const float4*)&ql[ig * 4 + 0][d4];
            const float4 q1 = *(const float4*)&ql[ig * 4 + 1][d4];
            const float4 q2 = *(const float4*)&ql[ig * 4 + 2][d4];
            const float4 q3 = *(const float4*)&ql[ig * 4 + 3][d4];
            a0 += q0.x * rk4.x + q0.y * rk4.y + q0.z * rk4.z + q0.w * rk4.w;
            a1 += q1.x * rk4.x + q1.y * rk4.y + q1.z * rk4.z + q1.w * rk4.w;
            a2 += q2.x * rk4.x + q2.y * rk4.y + q2.z * rk4.z + q2.w * rk4.w;
            a3 += q3.x * rk4.x + q3.y * rk4.y + q3.z * rk4.z + q3.w * rk4.w;
        }
        qrl[ig * 4 + 0][r] = a0;
        qrl[ig * 4 + 1][r] = a1;
        qrl[ig * 4 + 2][r] = a2;
        qrl[ig * 4 + 3][r] = a3;
    }
    __syncthreads();

    // ---- scores: thread t owns column j=t; K row loaded global->VGPR ----
    {
        const int j = t;
        const float* __restrict__ kro = &K[(b * TT + j) * DD + h * DKK];
        float4 kr[16];
        #pragma unroll
        for (int c = 0; c < 16; ++c) kr[c] = *(const float4*)&kro[c * 4];
        for (int i = 0; i < 16; ++i) {
            float a = 0.f;
            #pragma unroll
            for (int c = 0; c < 16; ++c) {
                const float4 q4 = *(const float4*)&ql[i][c * 4];
                a += q4.x * kr[c].x + q4.y * kr[c].y + q4.z * kr[c].z + q4.w * kr[c].w;
            }
            sl[i][j] = (a + qrl[i][smlp[i][j]]) * 0.125f;   // 1/sqrt(64)
        }
    }
    __syncthreads();

    // ---- softmax (16 lanes per row, shfl-xor width 16) + histogram ----
    {
        const int row = t >> 4, g = t & 15;
        float vals[16];
        float m = -1e30f;
        #pragma unroll
        for (int jj = 0; jj < 16; ++jj) {
            vals[jj] = sl[row][g + jj * 16];
            m = fmaxf(m, vals[jj]);
        }
        #pragma unroll
        for (int off = 8; off; off >>= 1) m = fmaxf(m, __shfl_xor(m, off, 16));
        float s = 0.f;
        #pragma unroll
        for (int jj = 0; jj < 16; ++jj) { vals[jj] = __expf(vals[jj] - m); s += vals[jj]; }
        #pragma unroll
        for (int off = 8; off; off >>= 1) s += __shfl_xor(s, off, 16);
        const float inv = 1.0f / s;
        #pragma unroll
        for (int jj = 0; jj < 16; ++jj) {
            const float p = vals[jj] * inv;
            sl[row][g + jj * 16] = p;
            atomicAdd(&wlh[row][smlp[row][g + jj * 16]], p);
        }
    }
    __syncthreads();

    // ---- PV: wave w owns j in [64w,64w+64); lane (dg,ig) owns i=4ig..+3, d=4dg..+3.
    // V streamed global->reg in 8-row chunks (32 VGPR); acc = 16 VGPR. No LDS V tile.
    {
        const int w = t >> 6, l = t & 63;
        const int dg = l & 15, ig = l >> 4;
        const int jb = w * 64;
        float4 a0 = {0,0,0,0}, a1 = {0,0,0,0}, a2 = {0,0,0,0}, a3 = {0,0,0,0};
        for (int c8 = 0; c8 < 8; ++c8) {
            const int j0 = jb + c8 * 8;
            float4 vr[8];
            #pragma unroll
            for (int u = 0; u < 8; ++u)
                vr[u] = *(const float4*)&V[(b * TT + j0 + u) * DD + h * DKK + dg * 4];
            #pragma unroll
            for (int ii = 0; ii < 4; ++ii) {
                const int i = ig * 4 + ii;
                const float4 pa = *(const float4*)&sl[i][j0];
                const float4 pb = *(const float4*)&sl[i][j0 + 4];
                float4& A = (ii == 0) ? a0 : (ii == 1) ? a1 : (ii == 2) ? a2 : a3;
                FMA4(A, pa.x, vr[0]); FMA4(A, pa.y, vr[1]);
                FMA4(A, pa.z, vr[2]); FMA4(A, pa.w, vr[3]);
                FMA4(A, pb.x, vr[4]); FMA4(A, pb.y, vr[5]);
                FMA4(A, pb.z, vr[6]); FMA4(A, pb.w, vr[7]);
            }
        }
        *(float4*)&aggp[w][ig * 4 + 0][dg * 4] = a0;
        *(float4*)&aggp[w][ig * 4 + 1][dg * 4] = a1;
        *(float4*)&aggp[w][ig * 4 + 2][dg * 4] = a2;
        *(float4*)&aggp[w][ig * 4 + 3][dg * 4] = a3;
    }
    __syncthreads();

    // ---- final: reduce 4 wave partials + histogram x rel_v (global, coalesced) ----
    {
        const int d = t & 63, g4 = t >> 6;
        const int ia = g4 * 4;
        float a0 = aggp[0][ia+0][d] + aggp[1][ia+0][d] + aggp[2][ia+0][d] + aggp[3][ia+0][d];
        float a1 = aggp[0][ia+1][d] + aggp[1][ia+1][d] + aggp[2][ia+1][d] + aggp[3][ia+1][d];
        float a2 = aggp[0][ia+2][d] + aggp[1][ia+2][d] + aggp[2][ia+2][d] + aggp[3][ia+2][d];
        float a3 = aggp[0][ia+3][d] + aggp[1][ia+3][d] + aggp[2][ia+3][d] + aggp[3][ia+3][d];
        #pragma unroll 4
        for (int r = 0; r < 64; ++r) {
            const float rv = relv[r * DD + h * DKK + d];
            a0 += wlh[ia + 0][r] * rv;
            a1 += wlh[ia + 1][r] * rv;
            a2 += wlh[ia + 2][r] * rv;
            a3 += wlh[ia + 3][r] * rv;
        }
        AGG[(b * TT + i0 + ia + 0) * DD + h * DKK + d] = a0;
        AGG[(b * TT + i0 + ia + 1) * DD + h * DKK + d] = a1;
        AGG[(b * TT + i0 + ia + 2) * DD + h * DKK + d] = a2;
        AGG[(b * TT + i0 + ia + 3) * DD + h * DKK + d] = a3;
    }
}

// ---------------- Kernel 3: out projection + bias + residual ----------------
__global__ __launch_bounds__(256) void k_oproj(
    const float* __restrict__ AGG, const float* __restrict__ Wo,
    const float* __restrict__ bo, const float* __restrict__ x,
    float* __restrict__ OPRE)
{
    const int r0 = blockIdx.x * 16, c0 = blockIdx.y * 64;
    __shared__ float al[16][68];
    __shared__ float wl[64][68];
    const int t = threadIdx.x;
    const int cg = t & 15, rg = t >> 4;
    float acc[4] = {};
    for (int kt = 0; kt < 4; ++kt) {
        const int kb = kt * 64;
        {
            const int r = t >> 4, q4 = t & 15;
            *(float4*)&al[r][q4 * 4] = *(const float4*)&AGG[(r0 + r) * DD + kb + q4 * 4];
        }
        #pragma unroll
        for (int u = 0; u < 4; ++u) {
            const int idx = u * 256 + t;
            const int r = idx >> 4, q4 = idx & 15;
            *(float4*)&wl[r][q4 * 4] = *(const float4*)&Wo[(c0 + r) * DD + kb + q4 * 4];
        }
        __syncthreads();
        #pragma unroll 4
        for (int d4 = 0; d4 < 64; d4 += 4) {
            const float4 av = *(const float4*)&al[rg][d4];
            #pragma unroll
            for (int c = 0; c < 4; ++c) {
                const float4 wv = *(const float4*)&wl[cg + 16 * c][d4];
                acc[c] += av.x * wv.x + av.y * wv.y + av.z * wv.z + av.w * wv.w;
            }
        }
        __syncthreads();
    }
    const int r = r0 + rg;
    #pragma unroll
    for (int c = 0; c < 4; ++c) {
        const int cc = c0 + cg + 16 * c;
        OPRE[r * DD + cc] = acc[c] + bo[cc] + x[r * DD + cc];
    }
}

// ---------------- Kernel 4: LayerNorm + ReLU (one wave per row) ----------------
__global__ __launch_bounds__(256) void k_ln(
    const float* __restrict__ OPRE, const float* __restrict__ gamma,
    const float* __restrict__ beta, float* __restrict__ out)
{
    const int row = blockIdx.x * 4 + (threadIdx.x >> 6);
    const int lane = threadIdx.x & 63;
    const float4 v = *(const float4*)&OPRE[row * DD + lane * 4];
    float s  = v.x + v.y + v.z + v.w;
    float sq = v.x * v.x + v.y * v.y + v.z * v.z + v.w * v.w;
    #pragma unroll
    for (int off = 32; off; off >>= 1) {
        s  += __shfl_xor(s, off, 64);
        sq += __shfl_xor(sq, off, 64);
    }
    const float mu   = s * (1.0f / DD);
    const float rstd = rsqrtf(sq * (1.0f / DD) - mu * mu + 1e-5f);
    const float4 g  = *(const float4*)&gamma[lane * 4];
    const float4 bt = *(const float4*)&beta[lane * 4];
    float4 o;
    o.x = fmaxf((v.x - mu) * rstd * g.x + bt.x, 0.f);
    o.y = fmaxf((v.y - mu) * rstd * g.y + bt.y, 0.f);
    o.z = fmaxf((v.z - mu) * rstd * g.z + bt.z, 0.f);
    o.w = fmaxf((v.w - mu) * rstd * g.w + bt.w, 0.f);
    *(float4*)&out[row * DD + lane * 4] = o;
}

extern "C" void kernel_launch(void* const* d_in, const int* in_sizes, int n_in,
                              void* d_out, int out_size, void* d_ws, size_t ws_size,
                              hipStream_t stream)
{
    (void)in_sizes; (void)n_in; (void)out_size; (void)ws_size;
    const float* x     = (const float*)d_in[0];
    const int*   SM    = (const int*)d_in[1];
    const float* Wq    = (const float*)d_in[2];
    const float* bq    = (const float*)d_in[3];
    const float* Wk    = (const float*)d_in[4];
    const float* bk    = (const float*)d_in[5];
    const float* Wv    = (const float*)d_in[6];
    const float* bv    = (const float*)d_in[7];
    const float* relk  = (const float*)d_in[8];
    const float* relv  = (const float*)d_in[9];
    const float* Wo    = (const float*)d_in[10];
    const float* bo    = (const float*)d_in[11];
    const float* gamma = (const float*)d_in[12];
    const float* beta  = (const float*)d_in[13];
    float* out = (float*)d_out;
    float* ws  = (float*)d_ws;

    const int NTD = NB * TT * DD;   // 262144 floats
    float* Q  = ws;
    float* K  = ws + NTD;
    float* V  = ws + 2 * NTD;
    float* AG = ws + 3 * NTD;
    float* OP = ws + 4 * NTD;

    k_qkv  <<<dim3(64, 4, 3), 256, 0, stream>>>(x, Wq, bq, Wk, bk, Wv, bv, Q, K, V);
    k_attn <<<dim3(16, NH, NB), 256, 0, stream>>>(Q, K, V, SM, relk, relv, AG);
    k_oproj<<<dim3(64, 4), 256, 0, stream>>>(AG, Wo, bo, x, OP);
    k_ln   <<<256, 256, 0, stream>>>(OP, gamma, beta, out);
}